// Round 10
// baseline (116.456 us; speedup 1.0000x reference)
//
#include <hip/hip_runtime.h>
#include <math.h>

#define KK 32
#define CC 256

// ---------------------------------------------------------------------------
// Kernel 1: blocks 0..127 = W2 tile-transpose -> W2t[c][o]; 128..639 = A rows
// (R7-verbatim reduction: A[o,k] = 0.5*rowsum_k + colsum_k - 0.5*W1[o,33k]),
// stored transposed At[k][o] so downstream reads are lane-coalesced.
// ---------------------------------------------------------------------------
__global__ __launch_bounds__(256) void prep_w_kernel(
    const float* __restrict__ W1, const float* __restrict__ W2,
    float* __restrict__ At, float* __restrict__ W2t)
{
    __shared__ float tile[64][65];
    const int t = threadIdx.x;

    if (blockIdx.x < 128) {
        // -------- transpose one 64(o) x 64(c) tile of W2 (1024x512) --------
        const int to = blockIdx.x >> 3, tc = blockIdx.x & 7;
        const int r  = t >> 2, c0 = (t & 3) * 16;
        #pragma unroll
        for (int u = 0; u < 4; ++u) {
            const float4 v = *(const float4*)(
                W2 + (size_t)(to * 64 + r) * 512 + tc * 64 + c0 + 4 * u);
            tile[r][c0 + 4 * u]     = v.x;
            tile[r][c0 + 4 * u + 1] = v.y;
            tile[r][c0 + 4 * u + 2] = v.z;
            tile[r][c0 + 4 * u + 3] = v.w;
        }
        __syncthreads();
        const int cw = t >> 2, o0 = (t & 3) * 16;
        #pragma unroll
        for (int u = 0; u < 4; ++u) {
            float4 w;
            w.x = tile[o0 + 4 * u][cw];
            w.y = tile[o0 + 4 * u + 1][cw];
            w.z = tile[o0 + 4 * u + 2][cw];
            w.w = tile[o0 + 4 * u + 3][cw];
            *(float4*)(W2t + (size_t)(tc * 64 + cw) * 1024 + to * 64 + o0 + 4 * u) = w;
        }
        return;
    }

    // -------- A rows: one W1 row per block (R7-verbatim values) --------
    float* rowlds = &tile[0][0];              // 1056 <= 64*65
    const int o = blockIdx.x - 128;           // 0..511
    if (t < 64) {
        const float* wr = W1 + (size_t)o * 1024;
        #pragma unroll
        for (int u = 0; u < 4; ++u) {
            const int e = t * 16 + u * 4;
            const float4 v = *(const float4*)(wr + e);
            const int f = (e >> 5) * 33 + (e & 31);
            rowlds[f] = v.x; rowlds[f + 1] = v.y;
            rowlds[f + 2] = v.z; rowlds[f + 3] = v.w;
        }
    }
    __syncthreads();
    if (t < 32) {
        float rs = 0.f, cs = 0.f;
        #pragma unroll
        for (int j = 0; j < 32; ++j) rs += rowlds[t * 33 + j];
        #pragma unroll
        for (int i = 0; i < 32; ++i) cs += rowlds[i * 33 + t];
        At[(size_t)t * 512 + o] = 0.5f * rs + cs - 0.5f * rowlds[t * 34];
    }
}

// ---------------------------------------------------------------------------
// Kernel 2: the whole per-(b,m) pipeline, 2 bm's per block, NO grid barriers
// (everything after the weight transforms is per-(b,m) local).
// Grid (32 m-pairs, 4 b), 256 threads, ~78 KB LDS.
//  P1: stage raw x (stride 258); means via R5's part8 reduction (bit-exact);
//      cov 2x2 tiles with INLINE centering (identical subtraction + fma chain
//      as R5's precentered version — adj>0 mask is knife-edge); adj -> out.
//  P2: h[o] = gelu(sum_k At[k][o]*mu[k]) — coalesced At reads, k-ascending.
//  P3: e[o] = sigmoid(sum_c W2t[c][4t..4t+3]*h[c]) — coalesced float4 W2t
//      reads (fixes R6's per-lane-row pattern), b128 LDS broadcasts of h,
//      c-ascending chain (bit-exact vs R5 mlp2); mask covm>0 into catt.
//  P4: per-row softmax + att @ x (R6's proven phase-D, raw xs).
// ---------------------------------------------------------------------------
__global__ __launch_bounds__(256) void fused_tail_kernel(
    const float* __restrict__ x, const float* __restrict__ At,
    const float* __restrict__ W2t, float* __restrict__ out,
    float* __restrict__ adj_out)
{
    __shared__ float xs[2][KK][258];     // 66,048 B (raw x, lives to P4)
    __shared__ float catt[2][KK][33];    //  8,448 B (covm -> masked e -> att)
    __shared__ float hsh[2][512];        //  4,096 B
    __shared__ float meanv[2][KK];
    __shared__ float part8[256];
    __shared__ float stdv[2][KK];

    const int t   = threadIdx.x;
    const int b   = blockIdx.y;
    const int m0  = blockIdx.x;          // 0..31
    const int bm0 = b * 64 + m0 * 2;

    // ---------------- P1: stage raw x ----------------
    #pragma unroll
    for (int mm = 0; mm < 2; ++mm) {
        const float* xp = x + (size_t)(bm0 + mm) * (KK * CC);
        #pragma unroll
        for (int s = 0; s < 8; ++s) {
            const int e = s * 1024 + t * 4;
            const float4 v = *(const float4*)(xp + e);
            const int i = e >> 8, col = e & 255;
            xs[mm][i][col] = v.x; xs[mm][i][col + 1] = v.y;
            xs[mm][i][col + 2] = v.z; xs[mm][i][col + 3] = v.w;
        }
    }
    __syncthreads();

    // means: R5's exact part8 reduction, per tile
    #pragma unroll
    for (int mm = 0; mm < 2; ++mm) {
        const int i = t >> 3, part = t & 7;
        float s = 0.f;
        const int c0 = part * 32;
        #pragma unroll
        for (int c = 0; c < 32; ++c) s += xs[mm][i][c0 + c];
        part8[t] = s;
        __syncthreads();
        if (t < KK) {
            float s2 = 0.f;
            #pragma unroll
            for (int k = 0; k < 8; ++k) s2 += part8[t * 8 + k];
            meanv[mm][t] = s2 * (1.0f / CC);
        }
        __syncthreads();
    }

    // cov upper-tri 2x2 tiles, inline centering (same bits as precentered)
    #pragma unroll
    for (int mm = 0; mm < 2; ++mm) {
        if (t < 136) {
            int rem = t, r = 0;
            while (rem >= 16 - r) { rem -= 16 - r; ++r; }
            const int ti = r, tj = r + rem;
            const int i0 = 2 * ti, i1 = i0 + 1, j0 = 2 * tj, j1 = j0 + 1;
            const float mi0 = meanv[mm][i0], mi1 = meanv[mm][i1];
            const float mj0 = meanv[mm][j0], mj1 = meanv[mm][j1];
            float c00 = 0.f, c01 = 0.f, c10 = 0.f, c11 = 0.f;
            for (int c = 0; c < CC; c += 2) {
                const float2 a0r = *(const float2*)&xs[mm][i0][c];
                const float2 a1r = *(const float2*)&xs[mm][i1][c];
                const float2 b0r = *(const float2*)&xs[mm][j0][c];
                const float2 b1r = *(const float2*)&xs[mm][j1][c];
                const float a0x = a0r.x - mi0, a0y = a0r.y - mi0;
                const float a1x = a1r.x - mi1, a1y = a1r.y - mi1;
                const float b0x = b0r.x - mj0, b0y = b0r.y - mj0;
                const float b1x = b1r.x - mj1, b1y = b1r.y - mj1;
                // sequential fma chain per accumulator — bit-exact vs R5
                c00 += a0x * b0x; c00 += a0y * b0y;
                c01 += a0x * b1x; c01 += a0y * b1y;
                c10 += a1x * b0x; c10 += a1y * b0y;
                c11 += a1x * b1x; c11 += a1y * b1y;
            }
            c00 *= (1.0f / (CC - 1)); c01 *= (1.0f / (CC - 1));
            c10 *= (1.0f / (CC - 1)); c11 *= (1.0f / (CC - 1));
            catt[mm][i0][j0] = c00; catt[mm][i0][j1] = c01;
            catt[mm][i1][j0] = c10; catt[mm][i1][j1] = c11;
            catt[mm][j0][i0] = c00; catt[mm][j1][i0] = c01;
            catt[mm][j0][i1] = c10; catt[mm][j1][i1] = c11;
        }
    }
    __syncthreads();
    if (t < 64) {
        const int mm = t >> 5, i = t & 31;
        stdv[mm][i] = sqrtf(catt[mm][i][i]);
    }
    __syncthreads();
    #pragma unroll
    for (int mm = 0; mm < 2; ++mm) {
        #pragma unroll
        for (int k = 0; k < 4; ++k) {
            const int pair = t + k * 256;
            const int i = pair >> 5, j = pair & 31;
            adj_out[(size_t)(bm0 + mm) * 1024 + pair] =
                catt[mm][i][j] / (stdv[mm][i] * stdv[mm][j]);
        }
    }

    // ---------------- P2: h = gelu(At^T @ mu) ----------------
    #pragma unroll
    for (int oq = 0; oq < 2; ++oq) {
        const int o = t + oq * 256;
        #pragma unroll
        for (int mm = 0; mm < 2; ++mm) {
            float a = 0.f;
            #pragma unroll
            for (int k = 0; k < 32; ++k)
                a += At[(size_t)k * 512 + o] * meanv[mm][k];   // k-ascending
            hsh[mm][o] = 0.5f * a * (1.0f + erff(a * 0.70710678118654752f));
        }
    }
    __syncthreads();

    // ---------------- P3: e = sigmoid(W2 @ h), masked into catt ----------------
    {
        const int o0 = 4 * t;                 // this thread's 4 o's
        const int i  = o0 >> 5, j0 = o0 & 31; // same att row for all 4
        float acc[2][4];
        #pragma unroll
        for (int q = 0; q < 4; ++q) { acc[0][q] = 0.f; acc[1][q] = 0.f; }
        for (int c = 0; c < 512; c += 4) {
            const float4 h0 = *(const float4*)&hsh[0][c];   // b128 broadcast
            const float4 h1 = *(const float4*)&hsh[1][c];
            const float4 w0 = *(const float4*)(W2t + (size_t)(c + 0) * 1024 + o0);
            const float4 w1 = *(const float4*)(W2t + (size_t)(c + 1) * 1024 + o0);
            const float4 w2 = *(const float4*)(W2t + (size_t)(c + 2) * 1024 + o0);
            const float4 w3 = *(const float4*)(W2t + (size_t)(c + 3) * 1024 + o0);
            const float* w0p = &w0.x; const float* w1p = &w1.x;
            const float* w2p = &w2.x; const float* w3p = &w3.x;
            #pragma unroll
            for (int q = 0; q < 4; ++q) {
                // c-ascending chain per accumulator — bit-exact vs R5 mlp2
                acc[0][q] += w0p[q] * h0.x; acc[0][q] += w1p[q] * h0.y;
                acc[0][q] += w2p[q] * h0.z; acc[0][q] += w3p[q] * h0.w;
                acc[1][q] += w0p[q] * h1.x; acc[1][q] += w1p[q] * h1.y;
                acc[1][q] += w2p[q] * h1.z; acc[1][q] += w3p[q] * h1.w;
            }
        }
        #pragma unroll
        for (int mm = 0; mm < 2; ++mm) {
            #pragma unroll
            for (int q = 0; q < 4; ++q) {
                const float ev = 1.0f / (1.0f + expf(-acc[mm][q]));
                const float cv = catt[mm][i][j0 + q];
                catt[mm][i][j0 + q] = (cv > 0.f) ? ev : -INFINITY;  // sign(adj)==sign(cov)
            }
        }
    }
    __syncthreads();

    // ---------------- P4: softmax rows + att @ x ----------------
    if (t < 64) {
        const int mm = t >> 5, i = t & 31;
        float mx = -INFINITY;
        #pragma unroll
        for (int j = 0; j < KK; ++j) mx = fmaxf(mx, catt[mm][i][j]);
        float s = 0.f;
        #pragma unroll
        for (int j = 0; j < KK; ++j) {
            const float v = expf(catt[mm][i][j] - mx);
            catt[mm][i][j] = v;
            s += v;
        }
        const float inv = 1.0f / s;
        #pragma unroll
        for (int j = 0; j < KK; ++j) catt[mm][i][j] *= inv;
    }
    __syncthreads();
    {
        const int mm = t >> 7;
        const int tt = t & 127;
        const int c8 = tt & 31, iq = tt >> 5;
        const int cA = 4 * c8, cB = 128 + 4 * c8;
        const int i0 = iq * 8;
        float4 accA[8], accB[8];
        #pragma unroll
        for (int r = 0; r < 8; ++r) {
            accA[r] = make_float4(0.f, 0.f, 0.f, 0.f);
            accB[r] = make_float4(0.f, 0.f, 0.f, 0.f);
        }
        for (int j = 0; j < KK; ++j) {
            const float2 xa0 = *(const float2*)&xs[mm][j][cA];
            const float2 xa1 = *(const float2*)&xs[mm][j][cA + 2];
            const float2 xb0 = *(const float2*)&xs[mm][j][cB];
            const float2 xb1 = *(const float2*)&xs[mm][j][cB + 2];
            #pragma unroll
            for (int r = 0; r < 8; ++r) {
                const float av = catt[mm][i0 + r][j];
                accA[r].x += av * xa0.x; accA[r].y += av * xa0.y;
                accA[r].z += av * xa1.x; accA[r].w += av * xa1.y;
                accB[r].x += av * xb0.x; accB[r].y += av * xb0.y;
                accB[r].z += av * xb1.x; accB[r].w += av * xb1.y;
            }
        }
        float* op = out + (size_t)(bm0 + mm) * (KK * CC);
        #pragma unroll
        for (int r = 0; r < 8; ++r) {
            *(float4*)(op + (size_t)(i0 + r) * CC + cA) = accA[r];
            *(float4*)(op + (size_t)(i0 + r) * CC + cB) = accB[r];
        }
    }
}

extern "C" void kernel_launch(void* const* d_in, const int* in_sizes, int n_in,
                              void* d_out, int out_size, void* d_ws, size_t ws_size,
                              hipStream_t stream) {
    const float* x  = (const float*)d_in[0];   // (4,64,32,256)
    const float* W1 = (const float*)d_in[1];   // (512,1024)
    const float* W2 = (const float*)d_in[2];   // (1024,512)
    float* out     = (float*)d_out;                       // 2,097,152 floats
    float* adj_out = out + (size_t)4 * 64 * 32 * 256;     // +262,144 floats

    float* At  = (float*)d_ws;                 // 32*512    =  16,384 floats
    float* W2t = At + 16384;                   // 512*1024  = 524,288 floats

    prep_w_kernel<<<640, 256, 0, stream>>>(W1, W2, At, W2t);
    fused_tail_kernel<<<dim3(32, 4), 256, 0, stream>>>(x, At, W2t, out, adj_out);
}